// Round 9
// baseline (974.843 us; speedup 1.0000x reference)
//
#include <hip/hip_runtime.h>

#define CDIM 64
#define HDIM 256
#define WDIM 256
#define HWSZ (HDIM * WDIM)
#define PAD 2
#define PW 260                      // padded row length
#define PPLANE ((size_t)PW * PW * 64)  // per-batch padded NHWC f16 elems

typedef _Float16 f16;
typedef f16  f16x8  __attribute__((ext_vector_type(8)));
typedef float f32x4 __attribute__((ext_vector_type(4)));

static __device__ __forceinline__ ushort f16bits(float v) {
    f16 h = (f16)v;
    return __builtin_bit_cast(ushort, h);
}

// ---------------------------------------------------------------------------
// Repack OIHW f32 -> [tap][oc][ic] f16 linear (validated round 7).
// ---------------------------------------------------------------------------
__global__ __launch_bounds__(256) void repack_wf16(const float* __restrict__ w,
                                                   ushort* __restrict__ wt, int TAPS) {
    int idx = blockIdx.x * 256 + threadIdx.x;
    if (idx >= 64 * 64 * TAPS) return;
    int tap = idx / 4096;
    int rem = idx - tap * 4096;
    int oc = rem >> 6, ic = rem & 63;
    wt[idx] = f16bits(w[(oc * 64 + ic) * TAPS + tap]);
}

// Cast 1x1 weights (200,64) -> [208][64] f16 zero-padded (validated r7/r8).
__global__ __launch_bounds__(256) void cast_w3(const float* __restrict__ w,
                                               ushort* __restrict__ wt) {
    int idx = blockIdx.x * 256 + threadIdx.x;
    if (idx >= 208 * 64) return;
    int oc = idx >> 6;
    wt[idx] = (oc < 200) ? f16bits(w[idx]) : (ushort)0;
}

// ---------------------------------------------------------------------------
// f32 NCHW -> padded NHWC f16, FULL plane (zero halo). One thread per pixel.
// ---------------------------------------------------------------------------
__global__ __launch_bounds__(256) void padc(const float* __restrict__ in,
                                            ushort* __restrict__ out) {
    int id = blockIdx.x * 256 + threadIdx.x;
    if (id >= PW * PW) return;
    const int b = blockIdx.z;
    int py = id / PW, px = id - py * PW;
    ushort* o = out + (size_t)b * PPLANE + (size_t)id * 64;
    int y = py - PAD, x = px - PAD;
    if (y >= 0 && y < HDIM && x >= 0 && x < WDIM) {
        const float* ib = in + (size_t)b * CDIM * HWSZ + y * WDIM + x;
#pragma unroll
        for (int c8 = 0; c8 < 8; ++c8) {
            f16x8 h;
#pragma unroll
            for (int j = 0; j < 8; ++j) h[j] = (f16)ib[(size_t)(c8 * 8 + j) * HWSZ];
            *(uint4*)(o + c8 * 8) = __builtin_bit_cast(uint4, h);
        }
    } else {
        uint4 z = make_uint4(0u, 0u, 0u, 0u);
#pragma unroll
        for (int c8 = 0; c8 < 8; ++c8) *(uint4*)(o + c8 * 8) = z;
    }
}

// Zero-fill (uint4 granules, grid-stride).
__global__ __launch_bounds__(256) void zfill(uint4* __restrict__ p, size_t n4) {
    size_t i = (size_t)blockIdx.x * 256 + threadIdx.x;
    const size_t stride = (size_t)gridDim.x * 256;
    uint4 z = make_uint4(0u, 0u, 0u, 0u);
    for (; i < n4; i += stride) p[i] = z;
}

// ---------------------------------------------------------------------------
// Streaming implicit-GEMM conv: NO LDS, NO barriers. All operands per-lane
// global_load_dwordx4 from the padded NHWC input (L1/L2-resident tap window)
// and linear [tap][64][64] weights. Tap loop fully unrolled (compile-time
// dy/dx) so the compiler pipelines loads across taps with counted vmcnt.
// Block: 256 thr = 4 waves = 4 pixel rows; tile 32x x 4y, all 64 oc.
// Per wave: 32 px x 64 oc = acc[2][4] fragments.
// Frag layout (16x16x32 f16): A lane=[m=lane&15][k=(lane>>4)*8+j];
// B=[n=lane&15][k]; D=[m=(lane>>4)*4+r][n=lane&15].
// ---------------------------------------------------------------------------
template <int KS, bool PRELU, bool F32OUT>
__global__ __launch_bounds__(256, 3) void conv_stream(
        const ushort* __restrict__ in,   // padded NHWC f16
        const ushort* __restrict__ wt,   // [tap][64][64] f16
        const float* __restrict__ bias,
        const float* __restrict__ alpha,
        const float* __restrict__ resid, // f32 NCHW (F32OUT only)
        void* __restrict__ outp) {
    constexpr int H = KS / 2;
    const int b   = blockIdx.z;
    const int x0  = blockIdx.x * 32;
    const int y0  = blockIdx.y * 4;
    const int tid = threadIdx.x;
    const int lane = tid & 63;
    const int wv  = tid >> 6;      // wave = pixel row
    const int lr  = lane & 15;
    const int hi  = lane >> 4;

    // base of this wave's input row window (top-left tap)
    const ushort* inb = in + (size_t)b * PPLANE
        + ((size_t)(y0 + wv + PAD - H) * PW + (x0 + PAD - H)) * 64;

    f32x4 acc[2][4] = {};

#pragma unroll
    for (int tap = 0; tap < KS * KS; ++tap) {
        const int dy = tap / KS, dx = tap - dy * KS;
        const ushort* ar = inb + (dy * PW + dx) * 64;
        const ushort* wr = wt + tap * 4096;
        f16x8 a[2][2], bf[4][2];
#pragma unroll
        for (int mf = 0; mf < 2; ++mf)
#pragma unroll
            for (int ks = 0; ks < 2; ++ks)
                a[mf][ks] = *(const f16x8*)(ar + (mf * 16 + lr) * 64 + ks * 32 + hi * 8);
#pragma unroll
        for (int nt = 0; nt < 4; ++nt)
#pragma unroll
            for (int ks = 0; ks < 2; ++ks)
                bf[nt][ks] = *(const f16x8*)(wr + (nt * 16 + lr) * 64 + ks * 32 + hi * 8);
#pragma unroll
        for (int ks = 0; ks < 2; ++ks)
#pragma unroll
            for (int mf = 0; mf < 2; ++mf)
#pragma unroll
                for (int nt = 0; nt < 4; ++nt)
                    acc[mf][nt] = __builtin_amdgcn_mfma_f32_16x16x32_f16(
                        a[mf][ks], bf[nt][ks], acc[mf][nt], 0, 0, 0);
    }

    // ---- epilogue ----
    const float al = PRELU ? alpha[0] : 0.f;
#pragma unroll
    for (int nt = 0; nt < 4; ++nt) {
        const int oc = nt * 16 + lr;
        const float bs = bias[oc];
#pragma unroll
        for (int mf = 0; mf < 2; ++mf) {
            if constexpr (!F32OUT) {
                // padded NHWC f16 interior write
                ushort* ob = (ushort*)outp + (size_t)b * PPLANE
                    + ((size_t)(y0 + wv + PAD) * PW + (x0 + mf * 16 + hi * 4 + PAD)) * 64 + oc;
#pragma unroll
                for (int r = 0; r < 4; ++r) {
                    float v = acc[mf][nt][r] + bs;
                    if constexpr (PRELU) v = (v >= 0.f) ? v : al * v;
                    ob[(size_t)r * 64] = f16bits(v);
                }
            } else {
                float* o = (float*)outp;
                size_t base = ((size_t)(b * CDIM + oc)) * HWSZ
                            + (size_t)(y0 + wv) * WDIM + x0 + mf * 16 + hi * 4;
                float4 sv = *(const float4*)(resid + base);
                float4 ov;
                ov.x = acc[mf][nt][0] + bs + sv.x;
                ov.y = acc[mf][nt][1] + bs + sv.y;
                ov.z = acc[mf][nt][2] + bs + sv.z;
                ov.w = acc[mf][nt][3] + bs + sv.w;
                *(float4*)(o + base) = ov;
            }
        }
    }
}

// ---------------------------------------------------------------------------
// ker = (r2 . W3t + tb3) * (g2 . W3g + gb3) via MFMA (validated r7/r8),
// adapted to padded NHWC inputs. Output ker f16 [65536][200].
// ---------------------------------------------------------------------------
__global__ __launch_bounds__(256, 2) void ker_mfma(
        const ushort* __restrict__ r2,   // padded NHWC f16 (batch slice)
        const ushort* __restrict__ g2,
        const ushort* __restrict__ w3t,  // [208][64] f16
        const float* __restrict__ tb3,
        const ushort* __restrict__ w3g,
        const float* __restrict__ gb3,
        ushort* __restrict__ ker) {
    const int tid  = threadIdx.x;
    const int lane = tid & 63;
    const int wv   = tid >> 6;
    const int lr   = lane & 15;
    const int hi   = lane >> 4;
    const int pixbase = blockIdx.x * 64 + wv * 16;
    const int y = pixbase >> 8, x0p = pixbase & 255;   // 16-aligned, no row wrap

    const size_t rowoff = ((size_t)(y + PAD) * PW + (x0p + PAD)) * 64;
    const ushort* arb = r2 + rowoff + (size_t)lr * 64;
    const ushort* agb = g2 + rowoff + (size_t)lr * 64;

    f32x4 accr[13] = {}, accg[13] = {};
#pragma unroll
    for (int ks = 0; ks < 2; ++ks) {
        f16x8 ar = *(const f16x8*)(arb + ks * 32 + hi * 8);
        f16x8 ag = *(const f16x8*)(agb + ks * 32 + hi * 8);
#pragma unroll
        for (int nt = 0; nt < 13; ++nt) {
            f16x8 bt = *(const f16x8*)(w3t + (nt * 16 + lr) * 64 + ks * 32 + hi * 8);
            f16x8 bg = *(const f16x8*)(w3g + (nt * 16 + lr) * 64 + ks * 32 + hi * 8);
            accr[nt] = __builtin_amdgcn_mfma_f32_16x16x32_f16(ar, bt, accr[nt], 0, 0, 0);
            accg[nt] = __builtin_amdgcn_mfma_f32_16x16x32_f16(ag, bg, accg[nt], 0, 0, 0);
        }
    }
#pragma unroll
    for (int nt = 0; nt < 13; ++nt) {
        const int oc = nt * 16 + lr;
        const bool ok = (oc < 200);
        const float bt = ok ? tb3[oc] : 0.f;
        const float bg = ok ? gb3[oc] : 0.f;
#pragma unroll
        for (int r = 0; r < 4; ++r) {
            const int p = pixbase + hi * 4 + r;
            float kv = (accr[nt][r] + bt) * (accg[nt][r] + bg);
            if (ok) ker[(size_t)p * 200 + oc] = f16bits(kv);
        }
    }
}

// ---------------------------------------------------------------------------
// 25-tap grouped apply (validated r7/r8): pixel-major LDS staging of f32
// NCHW source; writes padded NHWC f16 interior.
// ---------------------------------------------------------------------------
__global__ __launch_bounds__(256) void jbf_apply(
        const ushort* __restrict__ ker,  // [65536][200] f16
        const float* __restrict__ src,   // f32 NCHW batch slice
        ushort* __restrict__ out) {      // padded NHWC f16 batch slice
    __shared__ __align__(16) float sSrc[20 * 20 * 8];

    const int g0  = blockIdx.z * 4;
    const int tx0 = blockIdx.x * 16;
    const int ty0 = blockIdx.y * 16;
    const int tid = threadIdx.x;
    const int lx  = tid & 15;
    const int ly  = tid >> 4;
    const int pix = (ty0 + ly) * WDIM + (tx0 + lx);
    ushort* op = out + ((size_t)(ty0 + ly + PAD) * PW + (tx0 + lx + PAD)) * 64;

    for (int gi = 0; gi < 4; ++gi) {
        const int g = g0 + gi;
        __syncthreads();
        for (int i = tid; i < 3200; i += 256) {
            int c   = i / 400;
            int rem = i - c * 400;
            int yy  = rem / 20, xx = rem - yy * 20;
            int gy  = ty0 - 2 + yy, gx = tx0 - 2 + xx;
            float v = 0.f;
            if (gy >= 0 && gy < HDIM && gx >= 0 && gx < WDIM)
                v = src[(size_t)(g * 8 + c) * HWSZ + gy * WDIM + gx];
            sSrc[(yy * 20 + xx) * 8 + c] = v;
        }
        __syncthreads();

        float kt[25];
        const ushort* kp = ker + (size_t)pix * 200 + g * 25;
#pragma unroll
        for (int t = 0; t < 25; ++t)
            kt[t] = (float)(*(const f16*)(kp + t));

        float a8[8] = {};
#pragma unroll
        for (int t = 0; t < 25; ++t) {
            const int dy = t / 5, dx = t - dy * 5;
            const float* sp = &sSrc[((ly + dy) * 20 + (lx + dx)) * 8];
            f32x4 v0 = *(const f32x4*)sp;
            f32x4 v1 = *(const f32x4*)(sp + 4);
#pragma unroll
            for (int c = 0; c < 4; ++c) {
                a8[c]     = fmaf(kt[t], v0[c], a8[c]);
                a8[c + 4] = fmaf(kt[t], v1[c], a8[c + 4]);
            }
        }
        f16x8 h;
#pragma unroll
        for (int c = 0; c < 8; ++c) h[c] = (f16)a8[c];
        *(uint4*)(op + g * 8) = __builtin_bit_cast(uint4, h);
    }
}

// ---------------------------------------------------------------------------
extern "C" void kernel_launch(void* const* d_in, const int* in_sizes, int n_in,
                              void* d_out, int out_size, void* d_ws, size_t ws_size,
                              hipStream_t stream) {
    const float* source   = (const float*)d_in[0];
    const float* guidance = (const float*)d_in[1];
    const float* t_w1 = (const float*)d_in[2];
    const float* t_b1 = (const float*)d_in[3];
    const float* t_a1 = (const float*)d_in[4];
    const float* t_w2 = (const float*)d_in[5];
    const float* t_b2 = (const float*)d_in[6];
    const float* t_a2 = (const float*)d_in[7];
    const float* t_w3 = (const float*)d_in[8];
    const float* t_b3 = (const float*)d_in[9];
    const float* g_w1 = (const float*)d_in[10];
    const float* g_b1 = (const float*)d_in[11];
    const float* g_a1 = (const float*)d_in[12];
    const float* g_w2 = (const float*)d_in[13];
    const float* g_b2 = (const float*)d_in[14];
    const float* g_a2 = (const float*)d_in[15];
    const float* g_w3 = (const float*)d_in[16];
    const float* g_b3 = (const float*)d_in[17];
    const float* j_w1 = (const float*)d_in[18];
    const float* j_b1 = (const float*)d_in[19];
    const float* j_a1 = (const float*)d_in[20];
    const float* j_w2 = (const float*)d_in[21];
    const float* j_b2 = (const float*)d_in[22];

    // ws layout (ushort units): 3 padded NHWC f16 buffers (17.3 MB each) +
    // repacked weights (~1 MB) = ~53 MB. ker lives in d_out (consumed
    // before j1/j2 write it).
    ushort* P1    = (ushort*)d_ws;
    ushort* P2    = P1 + 2 * PPLANE;
    ushort* P3    = P2 + 2 * PPLANE;
    ushort* wt_t1 = P3 + 2 * PPLANE;
    ushort* wt_t2 = wt_t1 + 102400;
    ushort* wt_g1 = wt_t2 + 102400;
    ushort* wt_g2 = wt_g1 + 102400;
    ushort* wt_j1 = wt_g2 + 102400;
    ushort* wt_j2 = wt_j1 + 36864;
    ushort* w3t   = wt_j2 + 36864;
    ushort* w3g   = w3t + 13312;
    ushort* kerB  = (ushort*)d_out;

    repack_wf16<<<(64 * 64 * 25 + 255) / 256, 256, 0, stream>>>(t_w1, wt_t1, 25);
    repack_wf16<<<(64 * 64 * 25 + 255) / 256, 256, 0, stream>>>(t_w2, wt_t2, 25);
    repack_wf16<<<(64 * 64 * 25 + 255) / 256, 256, 0, stream>>>(g_w1, wt_g1, 25);
    repack_wf16<<<(64 * 64 * 25 + 255) / 256, 256, 0, stream>>>(g_w2, wt_g2, 25);
    repack_wf16<<<(64 * 64 * 9 + 255) / 256, 256, 0, stream>>>(j_w1, wt_j1, 9);
    repack_wf16<<<(64 * 64 * 9 + 255) / 256, 256, 0, stream>>>(j_w2, wt_j2, 9);
    cast_w3<<<(208 * 64 + 255) / 256, 256, 0, stream>>>(t_w3, w3t);
    cast_w3<<<(208 * 64 + 255) / 256, 256, 0, stream>>>(g_w3, w3g);

    dim3 blk(256);
    dim3 pgrid((PW * PW + 255) / 256, 1, 2);
    padc<<<pgrid, blk, 0, stream>>>(source, P1);
    padc<<<pgrid, blk, 0, stream>>>(guidance, P2);
    zfill<<<dim3(2048), blk, 0, stream>>>((uint4*)P3, (2 * PPLANE) / 8);

    dim3 cgrid(WDIM / 32, HDIM / 4, 2);   // 1024 blocks
    // target KG
    conv_stream<5, true,  false><<<cgrid, blk, 0, stream>>>(P1, wt_t1, t_b1, t_a1, nullptr, P3);
    conv_stream<5, true,  false><<<cgrid, blk, 0, stream>>>(P3, wt_t2, t_b2, t_a2, nullptr, P1); // r2 -> P1
    // guidance KG
    conv_stream<5, true,  false><<<cgrid, blk, 0, stream>>>(P2, wt_g1, g_b1, g_a1, nullptr, P3);
    conv_stream<5, true,  false><<<cgrid, blk, 0, stream>>>(P3, wt_g2, g_b2, g_a2, nullptr, P2); // g2 -> P2

    // per batch: bilateral kernel (MFMA) -> ker(d_out), then 25-tap apply -> P3
    dim3 agrid(HDIM / 16, WDIM / 16, 2);
    for (int b = 0; b < 2; ++b) {
        ker_mfma<<<dim3(HWSZ / 64), blk, 0, stream>>>(
            P1 + b * PPLANE, P2 + b * PPLANE, w3t, t_b3, w3g, g_b3, kerB);
        jbf_apply<<<agrid, blk, 0, stream>>>(
            kerB, source + (size_t)b * CDIM * HWSZ, P3 + b * PPLANE);
    }

    // output conv pair + residual
    conv_stream<3, true,  false><<<cgrid, blk, 0, stream>>>(P3, wt_j1, j_b1, j_a1, nullptr, P1);
    conv_stream<3, false, true ><<<cgrid, blk, 0, stream>>>(P1, wt_j2, j_b2, nullptr, source, d_out);
}